// Round 7
// baseline (3156.686 us; speedup 1.0000x reference)
//
#include <hip/hip_runtime.h>
#include <math.h>

#define B_   16
#define N_   2048
#define S_   1025
#define K_   16
#define EMB_ 64
#define NF_  (B_ * S_ * K_)   // 262400
#define NCH_ (NF_ / 64)       // 4100 column-chunks of 64

typedef float v2f __attribute__((ext_vector_type(2)));
typedef float v4f __attribute__((ext_vector_type(4)));

// ---------------- FPS: ONE WAVE per batch, fp32 bit-exact (validated pk-asm rounding) -------
// State: only dist[32] in VGPRs. Coords re-read each iteration from LDS, SoA float4 with
// XOR-ish swizzle phys = lane*8 + ((c+lane)&7) -> per-iter ds_read_b128 is conflict-free.
// Lane l owns contiguous points [l*32, l*32+32) -> (first lane via ballot, first local j) ==
// np.argmax lowest-index tie-break (tail logic byte-identical to validated round-6 version).
__global__ __launch_bounds__(64) void fps_kernel(const float* __restrict__ xy,
                                                 int* __restrict__ fps_idx,
                                                 float* __restrict__ new_xyz,
                                                 float* __restrict__ out0) {
  const int b = blockIdx.x;
  const int lane = threadIdx.x;   // 0..63
  __shared__ v4f lxs[512];        // 8 KB, swizzled x-coords
  __shared__ v4f lys[512];        // 8 KB, swizzled y-coords
  const float* xb = xy + (size_t)b * 2 * N_;
  float dist[32];
#pragma unroll
  for (int c = 0; c < 8; ++c) {
    const int p0 = lane * 32 + c * 4;
    v4f x4 = *reinterpret_cast<const v4f*>(&xb[p0]);
    v4f y4 = *reinterpret_cast<const v4f*>(&xb[N_ + p0]);
    const int ph = lane * 8 + ((c + lane) & 7);
    lxs[ph] = x4;
    lys[ph] = y4;
  }
#pragma unroll
  for (int j = 0; j < 32; ++j) dist[j] = __builtin_inff();
  __syncthreads();   // single wave; orders LDS init vs reads
  const float* lxf = reinterpret_cast<const float*>(lxs);
  const float* lyf = reinterpret_cast<const float*>(lys);
  int cur = 0;
  for (int t = 0; t < S_; ++t) {
    // centroid coords through the swizzled layout (uniform address -> broadcast)
    const int lo = cur >> 5, cc = (cur >> 2) & 7, sub = cur & 3;
    const int phe = (lo * 8 + ((cc + lo) & 7)) * 4 + sub;
    const float cx = lxf[phe], cy = lyf[phe];
    if (lane == 0) {
      fps_idx[b * S_ + t] = cur;
      new_xyz[(b * S_ + t) * 2 + 0] = cx;
      new_xyz[(b * S_ + t) * 2 + 1] = cy;
      out0[b * 2 * S_ + t] = cx;
      out0[b * 2 * S_ + S_ + t] = cy;
    }
    v2f ncx2; ncx2[0] = -cx; ncx2[1] = -cx;   // negation exact; pk_add(x,-c) == rn(x-c)
    v2f ncy2; ncy2[0] = -cy; ncy2[1] = -cy;
    float lmax = -__builtin_inff();
#pragma unroll
    for (int c = 0; c < 8; ++c) {
      const int ph = lane * 8 + ((c + lane) & 7);
      v4f x4 = lxs[ph];
      v4f y4 = lys[ph];
      v2f xl = __builtin_shufflevector(x4, x4, 0, 1);
      v2f xh = __builtin_shufflevector(x4, x4, 2, 3);
      v2f yl = __builtin_shufflevector(y4, y4, 0, 1);
      v2f yh = __builtin_shufflevector(y4, y4, 2, 3);
      v2f dx, dy, sx, sy, dd;
      asm("v_pk_add_f32 %0, %1, %2" : "=v"(dx) : "v"(xl), "v"(ncx2));
      asm("v_pk_add_f32 %0, %1, %2" : "=v"(dy) : "v"(yl), "v"(ncy2));
      asm("v_pk_mul_f32 %0, %1, %1" : "=v"(sx) : "v"(dx));
      asm("v_pk_mul_f32 %0, %1, %1" : "=v"(sy) : "v"(dy));
      asm("v_pk_add_f32 %0, %1, %2" : "=v"(dd) : "v"(sx), "v"(sy));
      float nd0 = fminf(dist[c * 4 + 0], dd[0]); dist[c * 4 + 0] = nd0;
      float nd1 = fminf(dist[c * 4 + 1], dd[1]); dist[c * 4 + 1] = nd1;
      asm("v_pk_add_f32 %0, %1, %2" : "=v"(dx) : "v"(xh), "v"(ncx2));
      asm("v_pk_add_f32 %0, %1, %2" : "=v"(dy) : "v"(yh), "v"(ncy2));
      asm("v_pk_mul_f32 %0, %1, %1" : "=v"(sx) : "v"(dx));
      asm("v_pk_mul_f32 %0, %1, %1" : "=v"(sy) : "v"(dy));
      asm("v_pk_add_f32 %0, %1, %2" : "=v"(dd) : "v"(sx), "v"(sy));
      float nd2 = fminf(dist[c * 4 + 2], dd[0]); dist[c * 4 + 2] = nd2;
      float nd3 = fminf(dist[c * 4 + 3], dd[1]); dist[c * 4 + 3] = nd3;
      lmax = fmaxf(fmaxf(lmax, fmaxf(nd0, nd1)), fmaxf(nd2, nd3));
    }
    // DPP max all-reduce to lane 63 (pure VALU)
    int xr = __float_as_int(lmax);
#define DPP_MAX_STEP(CTRL)                                                        \
    {                                                                             \
      int tmp_ = __builtin_amdgcn_update_dpp(xr, xr, (CTRL), 0xF, 0xF, false);    \
      xr = __float_as_int(fmaxf(__int_as_float(xr), __int_as_float(tmp_)));       \
    }
    DPP_MAX_STEP(0x111)  // row_shr:1
    DPP_MAX_STEP(0x112)  // row_shr:2
    DPP_MAX_STEP(0x114)  // row_shr:4
    DPP_MAX_STEP(0x118)  // row_shr:8
    DPP_MAX_STEP(0x142)  // row_bcast:15
    DPP_MAX_STEP(0x143)  // row_bcast:31 -> lane63 = global max
#undef DPP_MAX_STEP
    const float g = __int_as_float(__builtin_amdgcn_readlane(xr, 63));
    int lf = 0;
#pragma unroll
    for (int j = 31; j >= 0; --j)
      if (dist[j] == g) lf = j;             // descending scan keeps lowest j; == is exact
    unsigned long long mask = __ballot(lmax == g);   // non-empty by construction
    int first = __ffsll(mask) - 1;                   // lowest lane with the max
    cur = __builtin_amdgcn_readlane(lane * 32 + lf, first);
  }
}

// ---------------- KNN fp64-exact, 16 lanes per query point, register bitonic merges ----------
__global__ __launch_bounds__(256) void knn_kernel(const float* __restrict__ xy,
                                                  const int* __restrict__ fps_idx,
                                                  int* __restrict__ knn_sel) {
  const int b = blockIdx.y;
  __shared__ float2 lxy[N_];    // 16 KB
  __shared__ double lsq[N_];    // 16 KB
  const float* xb = xy + (size_t)b * 2 * N_;
  for (int p = threadIdx.x; p < N_; p += 256) {
    float x = xb[p], y = xb[N_ + p];
    lxy[p] = make_float2(x, y);
    lsq[p] = (double)x * (double)x + (double)y * (double)y;  // exact
  }
  __syncthreads();
  const int t = threadIdx.x;
  const int s = blockIdx.x * 16 + (t >> 4);
  if (s >= S_) return;
  const int oct = t & 15;
  const int p0 = fps_idx[b * S_ + s];
  float2 q = lxy[p0];
  const double xn = (double)q.x, yn = (double)q.y;
  const double sqn = lsq[p0];
  double d16[16];
  int i16[16];
#pragma unroll
  for (int j = 0; j < 16; ++j) { d16[j] = __builtin_inf(); i16[j] = 0x7fffffff; }
  const int mlo = oct * 128;
  for (int m0 = mlo; m0 < mlo + 128; m0 += 4) {
    double dd[4];
#pragma unroll
    for (int u = 0; u < 4; ++u) {
      float2 p = lxy[m0 + u];
      double dot = (double)p.x * xn + (double)p.y * yn;
      dd[u] = (sqn - 2.0 * dot) + lsq[m0 + u];
    }
#pragma unroll
    for (int u = 0; u < 4; ++u) {
      if (dd[u] < d16[15]) {
        double d = dd[u];
        int mi = m0 + u;
#pragma unroll
        for (int j = 15; j >= 1; --j) {
          bool shift = d < d16[j - 1];
          bool ins = d < d16[j];
          d16[j] = shift ? d16[j - 1] : (ins ? d : d16[j]);
          i16[j] = shift ? i16[j - 1] : (ins ? mi : i16[j]);
        }
        if (d < d16[0]) { d16[0] = d; i16[0] = mi; }
      }
    }
  }
#pragma unroll
  for (int w = 1; w <= 8; w <<= 1) {
    double nd[16]; int ni[16];
#pragma unroll
    for (int i = 0; i < 16; ++i) {
      double rd = __shfl_xor(d16[15 - i], w, 64);
      int ri = __shfl_xor(i16[15 - i], w, 64);
      bool takeR = (rd < d16[i]) || (rd == d16[i] && ri < i16[i]);
      nd[i] = takeR ? rd : d16[i];
      ni[i] = takeR ? ri : i16[i];
    }
#pragma unroll
    for (int i = 0; i < 16; ++i) { d16[i] = nd[i]; i16[i] = ni[i]; }
    if (w < 8) {
#pragma unroll
      for (int dstg = 8; dstg >= 1; dstg >>= 1) {
#pragma unroll
        for (int i = 0; i < 16; ++i) {
          if ((i & dstg) == 0) {
            int a = i, c = i + dstg;
            bool sw = (d16[a] > d16[c]) || (d16[a] == d16[c] && i16[a] > i16[c]);
            double tlo = sw ? d16[c] : d16[a];
            double thi = sw ? d16[a] : d16[c];
            int ulo = sw ? i16[c] : i16[a];
            int uhi = sw ? i16[a] : i16[c];
            d16[a] = tlo; d16[c] = thi; i16[a] = ulo; i16[c] = uhi;
          }
        }
      }
    }
  }
  if (oct == 0) {
    int* dst = knn_sel + ((size_t)b * S_ + s) * K_;
#pragma unroll
    for (int j = 0; j < 16; ++j) dst[j] = i16[j];
  }
}

// ---------------- P[b][pt][c] = sum_e W1[c][2+e] * fea[b][e][pt] ----------------
__global__ __launch_bounds__(256) void pk_kernel(const float* __restrict__ fea,
                                                 const float* __restrict__ W1,
                                                 float* __restrict__ P) {
  const int t = threadIdx.x;
  const int b = blockIdx.x >> 5;
  const int pt0 = (blockIdx.x & 31) << 6;
  __shared__ float W1L[64 * 64];   // [e][c]
  __shared__ float feaL[64 * 64];  // [e][pt]
#pragma unroll
  for (int p = 0; p < 16; ++p) {
    int idx = t + 256 * p;
    int c = idx >> 6, e = idx & 63;
    W1L[e * 64 + c] = W1[c * 66 + 2 + e];
    int r = (t >> 6) + 4 * p, cc = t & 63;
    feaL[r * 64 + cc] = fea[((size_t)b * 64 + r) * N_ + pt0 + cc];
  }
  __syncthreads();
  const int tpt = t & 15, tcq = t >> 4;
  float acc[4][4];
#pragma unroll
  for (int i = 0; i < 4; ++i)
#pragma unroll
    for (int j = 0; j < 4; ++j) acc[i][j] = 0.f;
  for (int e = 0; e < 64; ++e) {
    float4 a4 = *reinterpret_cast<const float4*>(&W1L[e * 64 + tcq * 4]);
    float4 b4 = *reinterpret_cast<const float4*>(&feaL[e * 64 + tpt * 4]);
    const float av[4] = {a4.x, a4.y, a4.z, a4.w};
    const float bvv[4] = {b4.x, b4.y, b4.z, b4.w};
#pragma unroll
    for (int i = 0; i < 4; ++i)
#pragma unroll
      for (int j = 0; j < 4; ++j) acc[i][j] = fmaf(av[i], bvv[j], acc[i][j]);
  }
#pragma unroll
  for (int j = 0; j < 4; ++j) {
    int pt = tpt * 4 + j;
    float4 v = {acc[0][j], acc[1][j], acc[2][j], acc[3][j]};
    *reinterpret_cast<float4*>(&P[((size_t)(b * N_ + pt0 + pt)) * 64 + tcq * 4]) = v;
  }
}

// ---------------- Y1[64][NF]: gather P + W1a*dxy + b1 ----------------
__global__ __launch_bounds__(256) void yk1_kernel(const float* __restrict__ xy,
                                                  const int* __restrict__ knn_sel,
                                                  const float* __restrict__ new_xyz,
                                                  const float* __restrict__ P,
                                                  const float* __restrict__ W1,
                                                  const float* __restrict__ b1,
                                                  float* __restrict__ Y1) {
  __shared__ float w0s[64], w1s[64], bbs[64];
  const int t = threadIdx.x;
  if (t < 64) { w0s[t] = W1[t * 66 + 0]; w1s[t] = W1[t * 66 + 1]; bbs[t] = b1[t]; }
  __syncthreads();
  const int n = blockIdx.x * 256 + t;
  const int bs = n >> 4;
  const int b = bs / S_;
  const int nbr = knn_sel[n];
  const float dx = xy[(size_t)b * 2 * N_ + nbr] - new_xyz[bs * 2 + 0];
  const float dy = xy[(size_t)b * 2 * N_ + N_ + nbr] - new_xyz[bs * 2 + 1];
  const float* prow = &P[((size_t)(b * N_ + nbr)) * 64];
  for (int c4 = 0; c4 < 64; c4 += 4) {
    float4 p4 = *reinterpret_cast<const float4*>(&prow[c4]);
    float v0 = p4.x + w0s[c4 + 0] * dx + w1s[c4 + 0] * dy + bbs[c4 + 0];
    float v1 = p4.y + w0s[c4 + 1] * dx + w1s[c4 + 1] * dy + bbs[c4 + 1];
    float v2 = p4.z + w0s[c4 + 2] * dx + w1s[c4 + 2] * dy + bbs[c4 + 2];
    float v3 = p4.w + w0s[c4 + 3] * dx + w1s[c4 + 3] * dy + bbs[c4 + 3];
    Y1[(size_t)(c4 + 0) * NF_ + n] = v0;
    Y1[(size_t)(c4 + 1) * NF_ + n] = v1;
    Y1[(size_t)(c4 + 2) * NF_ + n] = v2;
    Y1[(size_t)(c4 + 3) * NF_ + n] = v3;
  }
}

// ---------------- per-row sum + sumsq in one pass (fp64) ----------------
__global__ __launch_bounds__(1024) void rowstats_kernel(const float* __restrict__ Y,
                                                        double* __restrict__ sum_out,
                                                        double* __restrict__ sq_out) {
  const int r = blockIdx.x;
  const float* row = Y + (size_t)r * NF_;
  double s = 0.0, s2 = 0.0;
  for (int i = threadIdx.x * 4; i < NF_; i += 4096) {
    float4 v = *reinterpret_cast<const float4*>(&row[i]);
    double dx = v.x, dy = v.y, dz = v.z, dw = v.w;
    s += (dx + dy) + (dz + dw);
    s2 = fma(dx, dx, s2); s2 = fma(dy, dy, s2);
    s2 = fma(dz, dz, s2); s2 = fma(dw, dw, s2);
  }
  __shared__ double sh[1024], sh2[1024];
  sh[threadIdx.x] = s; sh2[threadIdx.x] = s2;
  __syncthreads();
  for (int o = 512; o > 0; o >>= 1) {
    if (threadIdx.x < o) {
      sh[threadIdx.x] += sh[threadIdx.x + o];
      sh2[threadIdx.x] += sh2[threadIdx.x + o];
    }
    __syncthreads();
  }
  if (threadIdx.x == 0) { sum_out[r] = sh[0]; sq_out[r] = sh2[0]; }
}

// ---------------- per-row sum of relu(A*y+Bc) ----------------
__global__ __launch_bounds__(1024) void rowsumaff_kernel(const float* __restrict__ Y,
                                                         const float* __restrict__ A,
                                                         const float* __restrict__ Bc,
                                                         double* __restrict__ out) {
  const int r = blockIdx.x;
  const float a = A[r], c = Bc[r];
  double s = 0.0;
  for (int i = threadIdx.x; i < NF_; i += 1024) {
    float v = fmaxf(fmaf(Y[(size_t)r * NF_ + i], a, c), 0.f);
    s += (double)v;
  }
  __shared__ double sh[1024];
  sh[threadIdx.x] = s;
  __syncthreads();
  for (int o = 512; o > 0; o >>= 1) {
    if (threadIdx.x < o) sh[threadIdx.x] += sh[threadIdx.x + o];
    __syncthreads();
  }
  if (threadIdx.x == 0) out[r] = sh[0];
}

// ---------------- A = g*rsqrt(var+eps); D = be - A*mu ----------------
// mode 1: muv = SUM, varraw = SUMSQ  -> mu = sum/NF, var = sumsq/NF - mu^2 (fp64-safe)
// mode 0: muv = mu,  varraw = centered sumsq -> var = varraw/NF
__global__ void absch_kernel(const double* __restrict__ muv, const double* __restrict__ varraw,
                             const float* __restrict__ g, const float* __restrict__ be,
                             float* __restrict__ A, float* __restrict__ D, int M, int mode) {
  int m = threadIdx.x;
  if (m >= M) return;
  double mu, var;
  if (mode) { mu = muv[m] * (1.0 / NF_); var = varraw[m] * (1.0 / NF_) - mu * mu; }
  else { mu = muv[m]; var = varraw[m] * (1.0 / NF_); }
  double a = (double)g[m] / sqrt(var + 1e-5);
  A[m] = (float)a;
  D[m] = (float)((double)be[m] - a * mu);
}

// ---------------- mu[m] = dot(W[m,:K], S)/NF ----------------
__global__ void meanlin_kernel(const float* __restrict__ W, const double* __restrict__ S,
                               double* __restrict__ mu, int M, int Kk) {
  int m = threadIdx.x;
  if (m >= M) return;
  double acc = 0.0;
  for (int k = 0; k < Kk; ++k) acc += (double)W[m * Kk + k] * S[k];
  mu[m] = acc * (1.0 / NF_);
}

// ---------------- reduce partials [P][M] -> double[M] ----------------
__global__ void red_kernel(const float* __restrict__ parts, double* __restrict__ out, int P, int M) {
  int m = threadIdx.x;
  if (m >= M) return;
  double a = 0.0;
  for (int p = 0; p < P; ++p) a += (double)parts[(size_t)p * M + m];
  out[m] = a;
}

// ============ GEMM2 pass kernels: y2[128][64cols] per chunk, x1 from Y1 on the fly ============
template <int MODE>  // 0: accumulate (y2-mu2')^2 ; 1: accumulate relu(A2*y2+D2)
__global__ __launch_bounds__(256) void pass2_kernel(const float* __restrict__ Y1,
                                                    const float* __restrict__ W2,
                                                    const float* __restrict__ A1v,
                                                    const float* __restrict__ Bc1v,
                                                    const double* __restrict__ mu2p,
                                                    const float* __restrict__ A2v,
                                                    const float* __restrict__ D2v,
                                                    float* __restrict__ parts) {
  __shared__ float W2L[64 * 128];
  __shared__ float ab[128];
  __shared__ float vpart[16][128];
  const int t = threadIdx.x;
#pragma unroll
  for (int p = 0; p < 32; ++p) {
    int idx = t + 256 * p;
    int m = idx >> 6, k = idx & 63;
    W2L[k * 128 + m] = W2[m * 64 + k];
  }
  if (t < 64) { ab[t] = A1v[t]; ab[64 + t] = Bc1v[t]; }
  const int tmA = t >> 4, tcA = t & 15;
  float par0[8], par1[8], vacc[8];
#pragma unroll
  for (int i = 0; i < 8; ++i) {
    int m = tmA * 8 + i;
    if (MODE == 0) { par0[i] = (float)mu2p[m]; par1[i] = 0.f; }
    else { par0[i] = A2v[m]; par1[i] = D2v[m]; }
    vacc[i] = 0.f;
  }
  __syncthreads();
  for (int ch = blockIdx.x; ch < NCH_; ch += 512) {
    const size_t n0 = (size_t)ch * 64;
    float acc[8][4];
#pragma unroll
    for (int i = 0; i < 8; ++i)
#pragma unroll
      for (int j = 0; j < 4; ++j) acc[i][j] = 0.f;
#pragma unroll 2
    for (int k = 0; k < 64; ++k) {
      float4 y4 = *reinterpret_cast<const float4*>(&Y1[(size_t)k * NF_ + n0 + tcA * 4]);
      float a1 = ab[k], c1 = ab[64 + k];
      float bx[4];
      bx[0] = fmaxf(fmaf(y4.x, a1, c1), 0.f);
      bx[1] = fmaxf(fmaf(y4.y, a1, c1), 0.f);
      bx[2] = fmaxf(fmaf(y4.z, a1, c1), 0.f);
      bx[3] = fmaxf(fmaf(y4.w, a1, c1), 0.f);
      const float4* ap = reinterpret_cast<const float4*>(&W2L[k * 128 + tmA * 8]);
      float4 a0 = ap[0], a4 = ap[1];
      const float av[8] = {a0.x, a0.y, a0.z, a0.w, a4.x, a4.y, a4.z, a4.w};
#pragma unroll
      for (int i = 0; i < 8; ++i)
#pragma unroll
        for (int j = 0; j < 4; ++j) acc[i][j] = fmaf(av[i], bx[j], acc[i][j]);
    }
#pragma unroll
    for (int i = 0; i < 8; ++i)
#pragma unroll
      for (int j = 0; j < 4; ++j) {
        if (MODE == 0) {
          float d = acc[i][j] - par0[i];
          vacc[i] = fmaf(d, d, vacc[i]);
        } else {
          vacc[i] += fmaxf(fmaf(acc[i][j], par0[i], par1[i]), 0.f);
        }
      }
  }
#pragma unroll
  for (int i = 0; i < 8; ++i) vpart[tcA][tmA * 8 + i] = vacc[i];
  __syncthreads();
  if (t < 128) {
    float s = 0.f;
    for (int q = 0; q < 16; ++q) s += vpart[q][t];
    parts[(size_t)blockIdx.x * 128 + t] = s;
  }
}

// ============ var3 pass: y3 = W3 * relu(A2*(W2*x1)+D2), accumulate (y3-mu3')^2 ============
__global__ __launch_bounds__(256) void var3_kernel(const float* __restrict__ Y1,
                                                   const float* __restrict__ W2,
                                                   const float* __restrict__ W3,
                                                   const float* __restrict__ A1v,
                                                   const float* __restrict__ Bc1v,
                                                   const float* __restrict__ A2v,
                                                   const float* __restrict__ D2v,
                                                   const double* __restrict__ mu3p,
                                                   float* __restrict__ parts) {
  __shared__ float W2L[64 * 128];
  __shared__ float ab[128];
  __shared__ float X2s[128 * 68];
  __shared__ float W3c[16 * 256];
  __shared__ float vpart3[8][256];
  const int t = threadIdx.x;
#pragma unroll
  for (int p = 0; p < 32; ++p) {
    int idx = t + 256 * p;
    int m = idx >> 6, k = idx & 63;
    W2L[k * 128 + m] = W2[m * 64 + k];
  }
  if (t < 64) { ab[t] = A1v[t]; ab[64 + t] = Bc1v[t]; }
  const int tmA = t >> 4, tcA = t & 15;
  const int tm3 = t & 31, tcol = t >> 5;
  float a2r[8], d2r[8], mu3[8], vacc[8];
#pragma unroll
  for (int i = 0; i < 8; ++i) {
    a2r[i] = A2v[tmA * 8 + i];
    d2r[i] = D2v[tmA * 8 + i];
    mu3[i] = (float)mu3p[tm3 * 8 + i];
    vacc[i] = 0.f;
  }
  __syncthreads();
  for (int ch = blockIdx.x; ch < NCH_; ch += 256) {
    const size_t n0 = (size_t)ch * 64;
    {
      float acc[8][4];
#pragma unroll
      for (int i = 0; i < 8; ++i)
#pragma unroll
        for (int j = 0; j < 4; ++j) acc[i][j] = 0.f;
#pragma unroll 2
      for (int k = 0; k < 64; ++k) {
        float4 y4 = *reinterpret_cast<const float4*>(&Y1[(size_t)k * NF_ + n0 + tcA * 4]);
        float a1 = ab[k], c1 = ab[64 + k];
        float bx[4];
        bx[0] = fmaxf(fmaf(y4.x, a1, c1), 0.f);
        bx[1] = fmaxf(fmaf(y4.y, a1, c1), 0.f);
        bx[2] = fmaxf(fmaf(y4.z, a1, c1), 0.f);
        bx[3] = fmaxf(fmaf(y4.w, a1, c1), 0.f);
        const float4* ap = reinterpret_cast<const float4*>(&W2L[k * 128 + tmA * 8]);
        float4 a0 = ap[0], a4 = ap[1];
        const float av[8] = {a0.x, a0.y, a0.z, a0.w, a4.x, a4.y, a4.z, a4.w};
#pragma unroll
        for (int i = 0; i < 8; ++i)
#pragma unroll
          for (int j = 0; j < 4; ++j) acc[i][j] = fmaf(av[i], bx[j], acc[i][j]);
      }
#pragma unroll
      for (int i = 0; i < 8; ++i) {
        float4 v;
        v.x = fmaxf(fmaf(acc[i][0], a2r[i], d2r[i]), 0.f);
        v.y = fmaxf(fmaf(acc[i][1], a2r[i], d2r[i]), 0.f);
        v.z = fmaxf(fmaf(acc[i][2], a2r[i], d2r[i]), 0.f);
        v.w = fmaxf(fmaf(acc[i][3], a2r[i], d2r[i]), 0.f);
        *reinterpret_cast<float4*>(&X2s[(tmA * 8 + i) * 68 + tcA * 4]) = v;
      }
    }
    __syncthreads();
    float acc3[8][8];
#pragma unroll
    for (int i = 0; i < 8; ++i)
#pragma unroll
      for (int j = 0; j < 8; ++j) acc3[i][j] = 0.f;
    for (int kc = 0; kc < 8; ++kc) {
#pragma unroll
      for (int q = 0; q < 4; ++q) {
        float4 w = *reinterpret_cast<const float4*>(&W3[(size_t)t * 128 + kc * 16 + q * 4]);
        W3c[(q * 4 + 0) * 256 + t] = w.x;
        W3c[(q * 4 + 1) * 256 + t] = w.y;
        W3c[(q * 4 + 2) * 256 + t] = w.z;
        W3c[(q * 4 + 3) * 256 + t] = w.w;
      }
      __syncthreads();
#pragma unroll
      for (int kk = 0; kk < 16; ++kk) {
        const float4* ap = reinterpret_cast<const float4*>(&W3c[kk * 256 + tm3 * 8]);
        float4 a0 = ap[0], a4 = ap[1];
        const float4* bp = reinterpret_cast<const float4*>(&X2s[(kc * 16 + kk) * 68 + tcol * 8]);
        float4 b0 = bp[0], b4 = bp[1];
        const float av[8] = {a0.x, a0.y, a0.z, a0.w, a4.x, a4.y, a4.z, a4.w};
        const float bw[8] = {b0.x, b0.y, b0.z, b0.w, b4.x, b4.y, b4.z, b4.w};
#pragma unroll
        for (int i = 0; i < 8; ++i)
#pragma unroll
          for (int j = 0; j < 8; ++j) acc3[i][j] = fmaf(av[i], bw[j], acc3[i][j]);
      }
      __syncthreads();
    }
#pragma unroll
    for (int i = 0; i < 8; ++i)
#pragma unroll
      for (int j = 0; j < 8; ++j) {
        float d = acc3[i][j] - mu3[i];
        vacc[i] = fmaf(d, d, vacc[i]);
      }
    __syncthreads();
  }
#pragma unroll
  for (int i = 0; i < 8; ++i) vpart3[tcol][tm3 * 8 + i] = vacc[i];
  __syncthreads();
  {
    float s = 0.f;
    for (int q = 0; q < 8; ++q) s += vpart3[q][t];
    parts[(size_t)blockIdx.x * 256 + t] = s;
  }
}

// ============ final pass: GEMM2 -> BN -> relu -> GEMM3 -> BN -> max over k -> relu -> out1 ============
__global__ __launch_bounds__(256) void final_kernel(const float* __restrict__ Y1,
                                                    const float* __restrict__ W2,
                                                    const float* __restrict__ W3,
                                                    const float* __restrict__ A1v,
                                                    const float* __restrict__ Bc1v,
                                                    const float* __restrict__ A2v,
                                                    const float* __restrict__ D2v,
                                                    const float* __restrict__ A3v,
                                                    const float* __restrict__ D3v,
                                                    float* __restrict__ out1) {
  __shared__ float W2L[64 * 128];   // aliased as W3c in phase B
  __shared__ float ab[128];
  __shared__ float X2s[128 * 68];
  float* W3c = W2L;
  const int t = threadIdx.x;
#pragma unroll
  for (int p = 0; p < 32; ++p) {
    int idx = t + 256 * p;
    int m = idx >> 6, k = idx & 63;
    W2L[k * 128 + m] = W2[m * 64 + k];
  }
  if (t < 64) { ab[t] = A1v[t]; ab[64 + t] = Bc1v[t]; }
  const int tmA = t >> 4, tcA = t & 15;
  const int tm3 = t & 31, tcol = t >> 5;
  float a2r[8], d2r[8], a3r[8], d3r[8];
#pragma unroll
  for (int i = 0; i < 8; ++i) {
    a2r[i] = A2v[tmA * 8 + i];
    d2r[i] = D2v[tmA * 8 + i];
    a3r[i] = A3v[tm3 * 8 + i];
    d3r[i] = D3v[tm3 * 8 + i];
  }
  __syncthreads();
  const int ch = blockIdx.x;
  const size_t n0 = (size_t)ch * 64;
  {
    float acc[8][4];
#pragma unroll
    for (int i = 0; i < 8; ++i)
#pragma unroll
      for (int j = 0; j < 4; ++j) acc[i][j] = 0.f;
#pragma unroll 2
    for (int k = 0; k < 64; ++k) {
      float4 y4 = *reinterpret_cast<const float4*>(&Y1[(size_t)k * NF_ + n0 + tcA * 4]);
      float a1 = ab[k], c1 = ab[64 + k];
      float bx[4];
      bx[0] = fmaxf(fmaf(y4.x, a1, c1), 0.f);
      bx[1] = fmaxf(fmaf(y4.y, a1, c1), 0.f);
      bx[2] = fmaxf(fmaf(y4.z, a1, c1), 0.f);
      bx[3] = fmaxf(fmaf(y4.w, a1, c1), 0.f);
      const float4* ap = reinterpret_cast<const float4*>(&W2L[k * 128 + tmA * 8]);
      float4 a0 = ap[0], a4 = ap[1];
      const float av[8] = {a0.x, a0.y, a0.z, a0.w, a4.x, a4.y, a4.z, a4.w};
#pragma unroll
      for (int i = 0; i < 8; ++i)
#pragma unroll
        for (int j = 0; j < 4; ++j) acc[i][j] = fmaf(av[i], bx[j], acc[i][j]);
    }
#pragma unroll
    for (int i = 0; i < 8; ++i) {
      float4 v;
      v.x = fmaxf(fmaf(acc[i][0], a2r[i], d2r[i]), 0.f);
      v.y = fmaxf(fmaf(acc[i][1], a2r[i], d2r[i]), 0.f);
      v.z = fmaxf(fmaf(acc[i][2], a2r[i], d2r[i]), 0.f);
      v.w = fmaxf(fmaf(acc[i][3], a2r[i], d2r[i]), 0.f);
      *reinterpret_cast<float4*>(&X2s[(tmA * 8 + i) * 68 + tcA * 4]) = v;
    }
  }
  __syncthreads();
  float acc3[8][8];
#pragma unroll
  for (int i = 0; i < 8; ++i)
#pragma unroll
    for (int j = 0; j < 8; ++j) acc3[i][j] = 0.f;
  for (int kc = 0; kc < 8; ++kc) {
#pragma unroll
    for (int q = 0; q < 4; ++q) {
      float4 w = *reinterpret_cast<const float4*>(&W3[(size_t)t * 128 + kc * 16 + q * 4]);
      W3c[(q * 4 + 0) * 256 + t] = w.x;
      W3c[(q * 4 + 1) * 256 + t] = w.y;
      W3c[(q * 4 + 2) * 256 + t] = w.z;
      W3c[(q * 4 + 3) * 256 + t] = w.w;
    }
    __syncthreads();
#pragma unroll
    for (int kk = 0; kk < 16; ++kk) {
      const float4* ap = reinterpret_cast<const float4*>(&W3c[kk * 256 + tm3 * 8]);
      float4 a0 = ap[0], a4 = ap[1];
      const float4* bp = reinterpret_cast<const float4*>(&X2s[(kc * 16 + kk) * 68 + tcol * 8]);
      float4 b0 = bp[0], b4 = bp[1];
      const float av[8] = {a0.x, a0.y, a0.z, a0.w, a4.x, a4.y, a4.z, a4.w};
      const float bw[8] = {b0.x, b0.y, b0.z, b0.w, b4.x, b4.y, b4.z, b4.w};
#pragma unroll
      for (int i = 0; i < 8; ++i)
#pragma unroll
        for (int j = 0; j < 8; ++j) acc3[i][j] = fmaf(av[i], bw[j], acc3[i][j]);
    }
    __syncthreads();
  }
#pragma unroll
  for (int i = 0; i < 8; ++i) {
    float mx = -__builtin_inff();
#pragma unroll
    for (int j = 0; j < 8; ++j) {
      float v = fmaf(acc3[i][j], a3r[i], d3r[i]);
      mx = fmaxf(mx, v);
    }
    float o = __shfl_xor(mx, 32, 64);
    mx = fmaxf(mx, o);
    if ((tcol & 1) == 0) {
      int g = tcol >> 1;
      int bs = ch * 4 + g;
      int b = bs / S_;
      int s = bs - b * S_;
      out1[((size_t)(b * 256 + tm3 * 8 + i)) * S_ + s] = fmaxf(mx, 0.f);
    }
  }
}

__global__ void diag_kernel(float* out, float v) {
  if (threadIdx.x == 0 && blockIdx.x == 0) out[0] = v;
}

extern "C" void kernel_launch(void* const* d_in, const int* in_sizes, int n_in,
                              void* d_out, int out_size, void* d_ws, size_t ws_size,
                              hipStream_t stream) {
  const float* xy  = (const float*)d_in[0];
  const float* fea = (const float*)d_in[1];
  const float* W1  = (const float*)d_in[2];
  const float* b1  = (const float*)d_in[3];
  const float* g1  = (const float*)d_in[4];
  const float* be1 = (const float*)d_in[5];
  const float* W2  = (const float*)d_in[6];
  const float* b2  = (const float*)d_in[7];
  const float* g2  = (const float*)d_in[8];
  const float* be2 = (const float*)d_in[9];
  const float* W3  = (const float*)d_in[10];
  const float* b3  = (const float*)d_in[11];
  const float* g3  = (const float*)d_in[12];
  const float* be3 = (const float*)d_in[13];
  (void)b2; (void)b3;
  float* out = (float*)d_out;
  float* out1 = out + B_ * 2 * S_;

  char* w = (char*)d_ws;
  size_t off = 0;
  auto take = [&](size_t bytes) -> void* {
    void* p = w + off;
    off += (bytes + 255) & ~(size_t)255;
    return p;
  };
  int*    fps_idx = (int*)take((size_t)B_ * S_ * 4);
  float*  new_xyz = (float*)take((size_t)B_ * S_ * 2 * 4);
  int*    knn_sel = (int*)take((size_t)NF_ * 4);
  float*  P       = (float*)take((size_t)B_ * N_ * 64 * 4);   // 8.4 MB
  float*  Y1      = (float*)take((size_t)64 * NF_ * 4);       // 67.2 MB
  double* Sy1     = (double*)take(64 * 8);
  double* Sq1     = (double*)take(64 * 8);
  float*  A1      = (float*)take(64 * 4);
  float*  Bc1     = (float*)take(64 * 4);
  double* S1      = (double*)take(64 * 8);
  double* mu2p    = (double*)take(128 * 8);
  float*  var2p   = (float*)take((size_t)512 * 128 * 4);
  double* var2r   = (double*)take(128 * 8);
  float*  A2      = (float*)take(128 * 4);
  float*  D2      = (float*)take(128 * 4);
  float*  s2p     = (float*)take((size_t)512 * 128 * 4);
  double* S2      = (double*)take(128 * 8);
  double* mu3p    = (double*)take(256 * 8);
  float*  var3p   = (float*)take((size_t)256 * 256 * 4);
  double* var3r   = (double*)take(256 * 8);
  float*  A3      = (float*)take(256 * 4);
  float*  D3      = (float*)take(256 * 4);

  if (off > ws_size) {
    diag_kernel<<<1, 64, 0, stream>>>(out, (float)(ws_size >> 20));
    return;
  }

  fps_kernel<<<B_, 64, 0, stream>>>(xy, fps_idx, new_xyz, out);
  knn_kernel<<<dim3((S_ + 15) / 16, B_), 256, 0, stream>>>(xy, fps_idx, knn_sel);
  pk_kernel<<<B_ * 32, 256, 0, stream>>>(fea, W1, P);
  yk1_kernel<<<NF_ / 256, 256, 0, stream>>>(xy, knn_sel, new_xyz, P, W1, b1, Y1);

  rowstats_kernel<<<64, 1024, 0, stream>>>(Y1, Sy1, Sq1);
  absch_kernel<<<1, 64, 0, stream>>>(Sy1, Sq1, g1, be1, A1, Bc1, 64, 1);
  rowsumaff_kernel<<<64, 1024, 0, stream>>>(Y1, A1, Bc1, S1);

  meanlin_kernel<<<1, 128, 0, stream>>>(W2, S1, mu2p, 128, 64);
  pass2_kernel<0><<<512, 256, 0, stream>>>(Y1, W2, A1, Bc1, mu2p, nullptr, nullptr, var2p);
  red_kernel<<<1, 128, 0, stream>>>(var2p, var2r, 512, 128);
  absch_kernel<<<1, 128, 0, stream>>>(mu2p, var2r, g2, be2, A2, D2, 128, 0);

  pass2_kernel<1><<<512, 256, 0, stream>>>(Y1, W2, A1, Bc1, nullptr, A2, D2, s2p);
  red_kernel<<<1, 128, 0, stream>>>(s2p, S2, 512, 128);
  meanlin_kernel<<<1, 256, 0, stream>>>(W3, S2, mu3p, 256, 128);

  var3_kernel<<<256, 256, 0, stream>>>(Y1, W2, W3, A1, Bc1, A2, D2, mu3p, var3p);
  red_kernel<<<1, 256, 0, stream>>>(var3p, var3r, 256, 256);
  absch_kernel<<<1, 256, 0, stream>>>(mu3p, var3r, g3, be3, A3, D3, 256, 0);

  final_kernel<<<NCH_, 256, 0, stream>>>(Y1, W2, W3, A1, Bc1, A2, D2, A3, D3, out1);
}

// Round 8
// 2568.630 us; speedup vs baseline: 1.2289x; 1.2289x over previous
//
#include <hip/hip_runtime.h>
#include <math.h>

#define B_   16
#define N_   2048
#define S_   1025
#define K_   16
#define EMB_ 64
#define NF_  (B_ * S_ * K_)   // 262400
#define NCH_ (NF_ / 64)       // 4100 column-chunks of 64

typedef float v2f __attribute__((ext_vector_type(2)));

// ---------------- FPS: ONE WAVE per batch, fp32 bit-exact (validated round-6 body) ----------
// d = rn(rn(dx*dx)+rn(dy*dy)), dx = rn(px+(-cx)). pk-asm only (no fma). Running fminf ==
// jnp.minimum; argmax lowest-index tie-break. Lane l owns [l*32, l*32+32).
// NEW: asm-pin px/py pairs (blocks rematerialization -> true VGPR residency) + waves_per_eu(1,1).
__global__ __launch_bounds__(64) __attribute__((amdgpu_waves_per_eu(1, 1)))
void fps_kernel(const float* __restrict__ xy,
                int* __restrict__ fps_idx,
                float* __restrict__ new_xyz,
                float* __restrict__ out0) {
  const int b = blockIdx.x;
  const int lane = threadIdx.x;   // 0..63
  __shared__ float2 lxy[N_];      // 16 KB (centroid lookup only)
  const float* xb = xy + (size_t)b * 2 * N_;
  const float2* xb2 = (const float2*)xb;
  const float2* yb2 = (const float2*)(xb + N_);
  v2f pxp[16], pyp[16];
  float dist[32];
#pragma unroll
  for (int q = 0; q < 16; ++q) {
    float2 x01 = xb2[lane * 16 + q];
    float2 y01 = yb2[lane * 16 + q];
    int p = lane * 32 + 2 * q;
    lxy[p] = make_float2(x01.x, y01.x);
    lxy[p + 1] = make_float2(x01.y, y01.y);
    pxp[q].x = x01.x; pxp[q].y = x01.y;
    pyp[q].x = y01.x; pyp[q].y = y01.y;
    dist[2 * q] = __builtin_inff();
    dist[2 * q + 1] = __builtin_inff();
  }
#pragma unroll
  for (int q = 0; q < 16; ++q) {   // opaque pin: forbids rematerialization of the loads
    asm volatile("" : "+v"(pxp[q]), "+v"(pyp[q]));
  }
  __syncthreads();
  int cur = 0;
  for (int t = 0; t < S_; ++t) {
    float2 c = lxy[cur];          // uniform-address broadcast read
    if (lane == 0) {
      fps_idx[b * S_ + t] = cur;
      new_xyz[(b * S_ + t) * 2 + 0] = c.x;
      new_xyz[(b * S_ + t) * 2 + 1] = c.y;
      out0[b * 2 * S_ + t] = c.x;
      out0[b * 2 * S_ + S_ + t] = c.y;
    }
    const float ncx = -c.x, ncy = -c.y;   // negation exact; pk_add(x,-c) == rn(x-c)
    v2f ncx2; ncx2[0] = ncx; ncx2[1] = ncx;
    v2f ncy2; ncy2[0] = ncy; ncy2[1] = ncy;
    float lmax0 = -__builtin_inff(), lmax1 = -__builtin_inff();
#pragma unroll
    for (int q = 0; q < 16; ++q) {
      v2f dx, dy, sx, sy, dd;
      asm("v_pk_add_f32 %0, %1, %2" : "=v"(dx) : "v"(pxp[q]), "v"(ncx2));
      asm("v_pk_add_f32 %0, %1, %2" : "=v"(dy) : "v"(pyp[q]), "v"(ncy2));
      asm("v_pk_mul_f32 %0, %1, %1" : "=v"(sx) : "v"(dx));
      asm("v_pk_mul_f32 %0, %1, %1" : "=v"(sy) : "v"(dy));
      asm("v_pk_add_f32 %0, %1, %2" : "=v"(dd) : "v"(sx), "v"(sy));
      float nd0 = fminf(dist[2 * q], dd[0]);
      float nd1 = fminf(dist[2 * q + 1], dd[1]);
      dist[2 * q] = nd0;
      dist[2 * q + 1] = nd1;
      lmax0 = fmaxf(lmax0, nd0);
      lmax1 = fmaxf(lmax1, nd1);
    }
    const float lmax = fmaxf(lmax0, lmax1);
    int xr = __float_as_int(lmax);
#define DPP_MAX_STEP(CTRL)                                                        \
    {                                                                             \
      int tmp_ = __builtin_amdgcn_update_dpp(xr, xr, (CTRL), 0xF, 0xF, false);    \
      xr = __float_as_int(fmaxf(__int_as_float(xr), __int_as_float(tmp_)));       \
    }
    DPP_MAX_STEP(0x111)  // row_shr:1
    DPP_MAX_STEP(0x112)  // row_shr:2
    DPP_MAX_STEP(0x114)  // row_shr:4
    DPP_MAX_STEP(0x118)  // row_shr:8
    DPP_MAX_STEP(0x142)  // row_bcast:15
    DPP_MAX_STEP(0x143)  // row_bcast:31 -> lane63 = global max
#undef DPP_MAX_STEP
    const float g = __int_as_float(__builtin_amdgcn_readlane(xr, 63));
    int lf = 0;
#pragma unroll
    for (int j = 31; j >= 0; --j)
      if (dist[j] == g) lf = j;             // descending scan keeps lowest j; == exact
    unsigned long long mask = __ballot(lmax == g);   // non-empty by construction
    int first = __ffsll(mask) - 1;                   // lowest lane with the max
    cur = __builtin_amdgcn_readlane(lane * 32 + lf, first);
  }
}

// ---------------- KNN fp64-exact, 16 lanes per query point (validated) ----------------
__global__ __launch_bounds__(256) void knn_kernel(const float* __restrict__ xy,
                                                  const int* __restrict__ fps_idx,
                                                  int* __restrict__ knn_sel) {
  const int b = blockIdx.y;
  __shared__ float2 lxy[N_];    // 16 KB
  __shared__ double lsq[N_];    // 16 KB
  const float* xb = xy + (size_t)b * 2 * N_;
  for (int p = threadIdx.x; p < N_; p += 256) {
    float x = xb[p], y = xb[N_ + p];
    lxy[p] = make_float2(x, y);
    lsq[p] = (double)x * (double)x + (double)y * (double)y;  // exact
  }
  __syncthreads();
  const int t = threadIdx.x;
  const int s = blockIdx.x * 16 + (t >> 4);
  if (s >= S_) return;
  const int oct = t & 15;
  const int p0 = fps_idx[b * S_ + s];
  float2 q = lxy[p0];
  const double xn = (double)q.x, yn = (double)q.y;
  const double sqn = lsq[p0];
  double d16[16];
  int i16[16];
#pragma unroll
  for (int j = 0; j < 16; ++j) { d16[j] = __builtin_inf(); i16[j] = 0x7fffffff; }
  const int mlo = oct * 128;
  for (int m0 = mlo; m0 < mlo + 128; m0 += 4) {
    double dd[4];
#pragma unroll
    for (int u = 0; u < 4; ++u) {
      float2 p = lxy[m0 + u];
      double dot = (double)p.x * xn + (double)p.y * yn;
      dd[u] = (sqn - 2.0 * dot) + lsq[m0 + u];
    }
#pragma unroll
    for (int u = 0; u < 4; ++u) {
      if (dd[u] < d16[15]) {
        double d = dd[u];
        int mi = m0 + u;
#pragma unroll
        for (int j = 15; j >= 1; --j) {
          bool shift = d < d16[j - 1];
          bool ins = d < d16[j];
          d16[j] = shift ? d16[j - 1] : (ins ? d : d16[j]);
          i16[j] = shift ? i16[j - 1] : (ins ? mi : i16[j]);
        }
        if (d < d16[0]) { d16[0] = d; i16[0] = mi; }
      }
    }
  }
#pragma unroll
  for (int w = 1; w <= 8; w <<= 1) {
    double nd[16]; int ni[16];
#pragma unroll
    for (int i = 0; i < 16; ++i) {
      double rd = __shfl_xor(d16[15 - i], w, 64);
      int ri = __shfl_xor(i16[15 - i], w, 64);
      bool takeR = (rd < d16[i]) || (rd == d16[i] && ri < i16[i]);
      nd[i] = takeR ? rd : d16[i];
      ni[i] = takeR ? ri : i16[i];
    }
#pragma unroll
    for (int i = 0; i < 16; ++i) { d16[i] = nd[i]; i16[i] = ni[i]; }
    if (w < 8) {
#pragma unroll
      for (int dstg = 8; dstg >= 1; dstg >>= 1) {
#pragma unroll
        for (int i = 0; i < 16; ++i) {
          if ((i & dstg) == 0) {
            int a = i, c = i + dstg;
            bool sw = (d16[a] > d16[c]) || (d16[a] == d16[c] && i16[a] > i16[c]);
            double tlo = sw ? d16[c] : d16[a];
            double thi = sw ? d16[a] : d16[c];
            int ulo = sw ? i16[c] : i16[a];
            int uhi = sw ? i16[a] : i16[c];
            d16[a] = tlo; d16[c] = thi; i16[a] = ulo; i16[c] = uhi;
          }
        }
      }
    }
  }
  if (oct == 0) {
    int* dst = knn_sel + ((size_t)b * S_ + s) * K_;
#pragma unroll
    for (int j = 0; j < 16; ++j) dst[j] = i16[j];
  }
}

// ---------------- P[b][pt][c] = sum_e W1[c][2+e] * fea[b][e][pt] ----------------
__global__ __launch_bounds__(256) void pk_kernel(const float* __restrict__ fea,
                                                 const float* __restrict__ W1,
                                                 float* __restrict__ P) {
  const int t = threadIdx.x;
  const int b = blockIdx.x >> 5;
  const int pt0 = (blockIdx.x & 31) << 6;
  __shared__ float W1L[64 * 64];   // [e][c]
  __shared__ float feaL[64 * 64];  // [e][pt]
#pragma unroll
  for (int p = 0; p < 16; ++p) {
    int idx = t + 256 * p;
    int c = idx >> 6, e = idx & 63;
    W1L[e * 64 + c] = W1[c * 66 + 2 + e];
    int r = (t >> 6) + 4 * p, cc = t & 63;
    feaL[r * 64 + cc] = fea[((size_t)b * 64 + r) * N_ + pt0 + cc];
  }
  __syncthreads();
  const int tpt = t & 15, tcq = t >> 4;
  float acc[4][4];
#pragma unroll
  for (int i = 0; i < 4; ++i)
#pragma unroll
    for (int j = 0; j < 4; ++j) acc[i][j] = 0.f;
  for (int e = 0; e < 64; ++e) {
    float4 a4 = *reinterpret_cast<const float4*>(&W1L[e * 64 + tcq * 4]);
    float4 b4 = *reinterpret_cast<const float4*>(&feaL[e * 64 + tpt * 4]);
    const float av[4] = {a4.x, a4.y, a4.z, a4.w};
    const float bvv[4] = {b4.x, b4.y, b4.z, b4.w};
#pragma unroll
    for (int i = 0; i < 4; ++i)
#pragma unroll
      for (int j = 0; j < 4; ++j) acc[i][j] = fmaf(av[i], bvv[j], acc[i][j]);
  }
#pragma unroll
  for (int j = 0; j < 4; ++j) {
    int pt = tpt * 4 + j;
    float4 v = {acc[0][j], acc[1][j], acc[2][j], acc[3][j]};
    *reinterpret_cast<float4*>(&P[((size_t)(b * N_ + pt0 + pt)) * 64 + tcq * 4]) = v;
  }
}

// ---------------- Y1[64][NF]: gather P + W1a*dxy + b1 ----------------
__global__ __launch_bounds__(256) void yk1_kernel(const float* __restrict__ xy,
                                                  const int* __restrict__ knn_sel,
                                                  const float* __restrict__ new_xyz,
                                                  const float* __restrict__ P,
                                                  const float* __restrict__ W1,
                                                  const float* __restrict__ b1,
                                                  float* __restrict__ Y1) {
  __shared__ float w0s[64], w1s[64], bbs[64];
  const int t = threadIdx.x;
  if (t < 64) { w0s[t] = W1[t * 66 + 0]; w1s[t] = W1[t * 66 + 1]; bbs[t] = b1[t]; }
  __syncthreads();
  const int n = blockIdx.x * 256 + t;
  const int bs = n >> 4;
  const int b = bs / S_;
  const int nbr = knn_sel[n];
  const float dx = xy[(size_t)b * 2 * N_ + nbr] - new_xyz[bs * 2 + 0];
  const float dy = xy[(size_t)b * 2 * N_ + N_ + nbr] - new_xyz[bs * 2 + 1];
  const float* prow = &P[((size_t)(b * N_ + nbr)) * 64];
  for (int c4 = 0; c4 < 64; c4 += 4) {
    float4 p4 = *reinterpret_cast<const float4*>(&prow[c4]);
    float v0 = p4.x + w0s[c4 + 0] * dx + w1s[c4 + 0] * dy + bbs[c4 + 0];
    float v1 = p4.y + w0s[c4 + 1] * dx + w1s[c4 + 1] * dy + bbs[c4 + 1];
    float v2 = p4.z + w0s[c4 + 2] * dx + w1s[c4 + 2] * dy + bbs[c4 + 2];
    float v3 = p4.w + w0s[c4 + 3] * dx + w1s[c4 + 3] * dy + bbs[c4 + 3];
    Y1[(size_t)(c4 + 0) * NF_ + n] = v0;
    Y1[(size_t)(c4 + 1) * NF_ + n] = v1;
    Y1[(size_t)(c4 + 2) * NF_ + n] = v2;
    Y1[(size_t)(c4 + 3) * NF_ + n] = v3;
  }
}

// ---------------- per-row sum + sumsq in one pass (fp64) ----------------
__global__ __launch_bounds__(1024) void rowstats_kernel(const float* __restrict__ Y,
                                                        double* __restrict__ sum_out,
                                                        double* __restrict__ sq_out) {
  const int r = blockIdx.x;
  const float* row = Y + (size_t)r * NF_;
  double s = 0.0, s2 = 0.0;
  for (int i = threadIdx.x * 4; i < NF_; i += 4096) {
    float4 v = *reinterpret_cast<const float4*>(&row[i]);
    double dx = v.x, dy = v.y, dz = v.z, dw = v.w;
    s += (dx + dy) + (dz + dw);
    s2 = fma(dx, dx, s2); s2 = fma(dy, dy, s2);
    s2 = fma(dz, dz, s2); s2 = fma(dw, dw, s2);
  }
  __shared__ double sh[1024], sh2[1024];
  sh[threadIdx.x] = s; sh2[threadIdx.x] = s2;
  __syncthreads();
  for (int o = 512; o > 0; o >>= 1) {
    if (threadIdx.x < o) {
      sh[threadIdx.x] += sh[threadIdx.x + o];
      sh2[threadIdx.x] += sh2[threadIdx.x + o];
    }
    __syncthreads();
  }
  if (threadIdx.x == 0) { sum_out[r] = sh[0]; sq_out[r] = sh2[0]; }
}

// ---------------- A = g*rsqrt(var+eps); D = be - A*mu (sum/sumsq form, validated r7) -------
__global__ void absch_kernel(const double* __restrict__ sumv, const double* __restrict__ sqv,
                             const float* __restrict__ g, const float* __restrict__ be,
                             float* __restrict__ A, float* __restrict__ D, int M) {
  int m = threadIdx.x;
  if (m >= M) return;
  double mu = sumv[m] * (1.0 / NF_);
  double var = sqv[m] * (1.0 / NF_) - mu * mu;
  double a = (double)g[m] / sqrt(var + 1e-5);
  A[m] = (float)a;
  D[m] = (float)((double)be[m] - a * mu);
}

// ---------------- reduce partials [P][2M] -> sum[M], sq[M] (fp64) ----------------
__global__ void redab_kernel(const float* __restrict__ parts, double* __restrict__ sum_out,
                             double* __restrict__ sq_out, int P, int M) {
  int m = threadIdx.x;
  if (m >= M) return;
  double a = 0.0, b = 0.0;
  for (int p = 0; p < P; ++p) {
    a += (double)parts[(size_t)p * 2 * M + m];
    b += (double)parts[(size_t)p * 2 * M + M + m];
  }
  sum_out[m] = a;
  sq_out[m] = b;
}

// ============ passA: GEMM2 per chunk, accumulate sum(y2), sum(y2^2) ============
__global__ __launch_bounds__(256) void passA_kernel(const float* __restrict__ Y1,
                                                    const float* __restrict__ W2,
                                                    const float* __restrict__ A1v,
                                                    const float* __restrict__ Bc1v,
                                                    float* __restrict__ parts) {
  __shared__ float W2L[64 * 128];
  __shared__ float ab[128];
  __shared__ float vpart[16][128];
  const int t = threadIdx.x;
#pragma unroll
  for (int p = 0; p < 32; ++p) {
    int idx = t + 256 * p;
    int m = idx >> 6, k = idx & 63;
    W2L[k * 128 + m] = W2[m * 64 + k];
  }
  if (t < 64) { ab[t] = A1v[t]; ab[64 + t] = Bc1v[t]; }
  const int tmA = t >> 4, tcA = t & 15;
  float vs[8], vq[8];
#pragma unroll
  for (int i = 0; i < 8; ++i) { vs[i] = 0.f; vq[i] = 0.f; }
  __syncthreads();
  for (int ch = blockIdx.x; ch < NCH_; ch += 512) {
    const size_t n0 = (size_t)ch * 64;
    float acc[8][4];
#pragma unroll
    for (int i = 0; i < 8; ++i)
#pragma unroll
      for (int j = 0; j < 4; ++j) acc[i][j] = 0.f;
#pragma unroll 2
    for (int k = 0; k < 64; ++k) {
      float4 y4 = *reinterpret_cast<const float4*>(&Y1[(size_t)k * NF_ + n0 + tcA * 4]);
      float a1 = ab[k], c1 = ab[64 + k];
      float bx[4];
      bx[0] = fmaxf(fmaf(y4.x, a1, c1), 0.f);
      bx[1] = fmaxf(fmaf(y4.y, a1, c1), 0.f);
      bx[2] = fmaxf(fmaf(y4.z, a1, c1), 0.f);
      bx[3] = fmaxf(fmaf(y4.w, a1, c1), 0.f);
      const float4* ap = reinterpret_cast<const float4*>(&W2L[k * 128 + tmA * 8]);
      float4 a0 = ap[0], a4 = ap[1];
      const float av[8] = {a0.x, a0.y, a0.z, a0.w, a4.x, a4.y, a4.z, a4.w};
#pragma unroll
      for (int i = 0; i < 8; ++i)
#pragma unroll
        for (int j = 0; j < 4; ++j) acc[i][j] = fmaf(av[i], bx[j], acc[i][j]);
    }
#pragma unroll
    for (int i = 0; i < 8; ++i)
#pragma unroll
      for (int j = 0; j < 4; ++j) {
        float y = acc[i][j];
        vs[i] += y;
        vq[i] = fmaf(y, y, vq[i]);
      }
  }
#pragma unroll
  for (int i = 0; i < 8; ++i) vpart[tcA][tmA * 8 + i] = vs[i];
  __syncthreads();
  if (t < 128) {
    float s = 0.f;
    for (int q = 0; q < 16; ++q) s += vpart[q][t];
    parts[(size_t)blockIdx.x * 256 + t] = s;
  }
  __syncthreads();
#pragma unroll
  for (int i = 0; i < 8; ++i) vpart[tcA][tmA * 8 + i] = vq[i];
  __syncthreads();
  if (t < 128) {
    float s = 0.f;
    for (int q = 0; q < 16; ++q) s += vpart[q][t];
    parts[(size_t)blockIdx.x * 256 + 128 + t] = s;
  }
}

// ============ passB: GEMM2 -> x2 -> GEMM3 per chunk, accumulate sum(y3), sum(y3^2) ============
__global__ __launch_bounds__(256) void passB_kernel(const float* __restrict__ Y1,
                                                    const float* __restrict__ W2,
                                                    const float* __restrict__ W3,
                                                    const float* __restrict__ A1v,
                                                    const float* __restrict__ Bc1v,
                                                    const float* __restrict__ A2v,
                                                    const float* __restrict__ D2v,
                                                    float* __restrict__ parts) {
  __shared__ float W2L[64 * 128];
  __shared__ float ab[128];
  __shared__ float X2s[128 * 68];
  __shared__ float W3c[16 * 256];
  __shared__ float vpart3[8][256];
  const int t = threadIdx.x;
#pragma unroll
  for (int p = 0; p < 32; ++p) {
    int idx = t + 256 * p;
    int m = idx >> 6, k = idx & 63;
    W2L[k * 128 + m] = W2[m * 64 + k];
  }
  if (t < 64) { ab[t] = A1v[t]; ab[64 + t] = Bc1v[t]; }
  const int tmA = t >> 4, tcA = t & 15;
  const int tm3 = t & 31, tcol = t >> 5;
  float a2r[8], d2r[8], vs[8], vq[8];
#pragma unroll
  for (int i = 0; i < 8; ++i) {
    a2r[i] = A2v[tmA * 8 + i];
    d2r[i] = D2v[tmA * 8 + i];
    vs[i] = 0.f; vq[i] = 0.f;
  }
  __syncthreads();
  for (int ch = blockIdx.x; ch < NCH_; ch += 256) {
    const size_t n0 = (size_t)ch * 64;
    {
      float acc[8][4];
#pragma unroll
      for (int i = 0; i < 8; ++i)
#pragma unroll
        for (int j = 0; j < 4; ++j) acc[i][j] = 0.f;
#pragma unroll 2
      for (int k = 0; k < 64; ++k) {
        float4 y4 = *reinterpret_cast<const float4*>(&Y1[(size_t)k * NF_ + n0 + tcA * 4]);
        float a1 = ab[k], c1 = ab[64 + k];
        float bx[4];
        bx[0] = fmaxf(fmaf(y4.x, a1, c1), 0.f);
        bx[1] = fmaxf(fmaf(y4.y, a1, c1), 0.f);
        bx[2] = fmaxf(fmaf(y4.z, a1, c1), 0.f);
        bx[3] = fmaxf(fmaf(y4.w, a1, c1), 0.f);
        const float4* ap = reinterpret_cast<const float4*>(&W2L[k * 128 + tmA * 8]);
        float4 a0 = ap[0], a4 = ap[1];
        const float av[8] = {a0.x, a0.y, a0.z, a0.w, a4.x, a4.y, a4.z, a4.w};
#pragma unroll
        for (int i = 0; i < 8; ++i)
#pragma unroll
          for (int j = 0; j < 4; ++j) acc[i][j] = fmaf(av[i], bx[j], acc[i][j]);
      }
#pragma unroll
      for (int i = 0; i < 8; ++i) {
        float4 v;
        v.x = fmaxf(fmaf(acc[i][0], a2r[i], d2r[i]), 0.f);
        v.y = fmaxf(fmaf(acc[i][1], a2r[i], d2r[i]), 0.f);
        v.z = fmaxf(fmaf(acc[i][2], a2r[i], d2r[i]), 0.f);
        v.w = fmaxf(fmaf(acc[i][3], a2r[i], d2r[i]), 0.f);
        *reinterpret_cast<float4*>(&X2s[(tmA * 8 + i) * 68 + tcA * 4]) = v;
      }
    }
    __syncthreads();
    float acc3[8][8];
#pragma unroll
    for (int i = 0; i < 8; ++i)
#pragma unroll
      for (int j = 0; j < 8; ++j) acc3[i][j] = 0.f;
    for (int kc = 0; kc < 8; ++kc) {
#pragma unroll
      for (int q = 0; q < 4; ++q) {
        float4 w = *reinterpret_cast<const float4*>(&W3[(size_t)t * 128 + kc * 16 + q * 4]);
        W3c[(q * 4 + 0) * 256 + t] = w.x;
        W3c[(q * 4 + 1) * 256 + t] = w.y;
        W3c[(q * 4 + 2) * 256 + t] = w.z;
        W3c[(q * 4 + 3) * 256 + t] = w.w;
      }
      __syncthreads();
#pragma unroll
      for (int kk = 0; kk < 16; ++kk) {
        const float4* ap = reinterpret_cast<const float4*>(&W3c[kk * 256 + tm3 * 8]);
        float4 a0 = ap[0], a4 = ap[1];
        const float4* bp = reinterpret_cast<const float4*>(&X2s[(kc * 16 + kk) * 68 + tcol * 8]);
        float4 b0 = bp[0], b4 = bp[1];
        const float av[8] = {a0.x, a0.y, a0.z, a0.w, a4.x, a4.y, a4.z, a4.w};
        const float bw[8] = {b0.x, b0.y, b0.z, b0.w, b4.x, b4.y, b4.z, b4.w};
#pragma unroll
        for (int i = 0; i < 8; ++i)
#pragma unroll
          for (int j = 0; j < 8; ++j) acc3[i][j] = fmaf(av[i], bw[j], acc3[i][j]);
      }
      __syncthreads();
    }
#pragma unroll
    for (int i = 0; i < 8; ++i)
#pragma unroll
      for (int j = 0; j < 8; ++j) {
        float y = acc3[i][j];
        vs[i] += y;
        vq[i] = fmaf(y, y, vq[i]);
      }
    __syncthreads();
  }
#pragma unroll
  for (int i = 0; i < 8; ++i) vpart3[tcol][tm3 * 8 + i] = vs[i];
  __syncthreads();
  {
    float s = 0.f;
    for (int q = 0; q < 8; ++q) s += vpart3[q][t];
    parts[(size_t)blockIdx.x * 512 + t] = s;
  }
  __syncthreads();
#pragma unroll
  for (int i = 0; i < 8; ++i) vpart3[tcol][tm3 * 8 + i] = vq[i];
  __syncthreads();
  {
    float s = 0.f;
    for (int q = 0; q < 8; ++q) s += vpart3[q][t];
    parts[(size_t)blockIdx.x * 512 + 256 + t] = s;
  }
}

// ============ final pass: GEMM2 -> BN -> relu -> GEMM3 -> BN -> max over k -> relu ============
__global__ __launch_bounds__(256) void final_kernel(const float* __restrict__ Y1,
                                                    const float* __restrict__ W2,
                                                    const float* __restrict__ W3,
                                                    const float* __restrict__ A1v,
                                                    const float* __restrict__ Bc1v,
                                                    const float* __restrict__ A2v,
                                                    const float* __restrict__ D2v,
                                                    const float* __restrict__ A3v,
                                                    const float* __restrict__ D3v,
                                                    float* __restrict__ out1) {
  __shared__ float W2L[64 * 128];   // aliased as W3c in phase B
  __shared__ float ab[128];
  __shared__ float X2s[128 * 68];
  float* W3c = W2L;
  const int t = threadIdx.x;
#pragma unroll
  for (int p = 0; p < 32; ++p) {
    int idx = t + 256 * p;
    int m = idx >> 6, k = idx & 63;
    W2L[k * 128 + m] = W2[m * 64 + k];
  }
  if (t < 64) { ab[t] = A1v[t]; ab[64 + t] = Bc1v[t]; }
  const int tmA = t >> 4, tcA = t & 15;
  const int tm3 = t & 31, tcol = t >> 5;
  float a2r[8], d2r[8], a3r[8], d3r[8];
#pragma unroll
  for (int i = 0; i < 8; ++i) {
    a2r[i] = A2v[tmA * 8 + i];
    d2r[i] = D2v[tmA * 8 + i];
    a3r[i] = A3v[tm3 * 8 + i];
    d3r[i] = D3v[tm3 * 8 + i];
  }
  __syncthreads();
  const int ch = blockIdx.x;
  const size_t n0 = (size_t)ch * 64;
  {
    float acc[8][4];
#pragma unroll
    for (int i = 0; i < 8; ++i)
#pragma unroll
      for (int j = 0; j < 4; ++j) acc[i][j] = 0.f;
#pragma unroll 2
    for (int k = 0; k < 64; ++k) {
      float4 y4 = *reinterpret_cast<const float4*>(&Y1[(size_t)k * NF_ + n0 + tcA * 4]);
      float a1 = ab[k], c1 = ab[64 + k];
      float bx[4];
      bx[0] = fmaxf(fmaf(y4.x, a1, c1), 0.f);
      bx[1] = fmaxf(fmaf(y4.y, a1, c1), 0.f);
      bx[2] = fmaxf(fmaf(y4.z, a1, c1), 0.f);
      bx[3] = fmaxf(fmaf(y4.w, a1, c1), 0.f);
      const float4* ap = reinterpret_cast<const float4*>(&W2L[k * 128 + tmA * 8]);
      float4 a0 = ap[0], a4 = ap[1];
      const float av[8] = {a0.x, a0.y, a0.z, a0.w, a4.x, a4.y, a4.z, a4.w};
#pragma unroll
      for (int i = 0; i < 8; ++i)
#pragma unroll
        for (int j = 0; j < 4; ++j) acc[i][j] = fmaf(av[i], bx[j], acc[i][j]);
    }
#pragma unroll
    for (int i = 0; i < 8; ++i) {
      float4 v;
      v.x = fmaxf(fmaf(acc[i][0], a2r[i], d2r[i]), 0.f);
      v.y = fmaxf(fmaf(acc[i][1], a2r[i], d2r[i]), 0.f);
      v.z = fmaxf(fmaf(acc[i][2], a2r[i], d2r[i]), 0.f);
      v.w = fmaxf(fmaf(acc[i][3], a2r[i], d2r[i]), 0.f);
      *reinterpret_cast<float4*>(&X2s[(tmA * 8 + i) * 68 + tcA * 4]) = v;
    }
  }
  __syncthreads();
  float acc3[8][8];
#pragma unroll
  for (int i = 0; i < 8; ++i)
#pragma unroll
    for (int j = 0; j < 8; ++j) acc3[i][j] = 0.f;
  for (int kc = 0; kc < 8; ++kc) {
#pragma unroll
    for (int q = 0; q < 4; ++q) {
      float4 w = *reinterpret_cast<const float4*>(&W3[(size_t)t * 128 + kc * 16 + q * 4]);
      W3c[(q * 4 + 0) * 256 + t] = w.x;
      W3c[(q * 4 + 1) * 256 + t] = w.y;
      W3c[(q * 4 + 2) * 256 + t] = w.z;
      W3c[(q * 4 + 3) * 256 + t] = w.w;
    }
    __syncthreads();
#pragma unroll
    for (int kk = 0; kk < 16; ++kk) {
      const float4* ap = reinterpret_cast<const float4*>(&W3c[kk * 256 + tm3 * 8]);
      float4 a0 = ap[0], a4 = ap[1];
      const float4* bp = reinterpret_cast<const float4*>(&X2s[(kc * 16 + kk) * 68 + tcol * 8]);
      float4 b0 = bp[0], b4 = bp[1];
      const float av[8] = {a0.x, a0.y, a0.z, a0.w, a4.x, a4.y, a4.z, a4.w};
      const float bw[8] = {b0.x, b0.y, b0.z, b0.w, b4.x, b4.y, b4.z, b4.w};
#pragma unroll
      for (int i = 0; i < 8; ++i)
#pragma unroll
        for (int j = 0; j < 8; ++j) acc3[i][j] = fmaf(av[i], bw[j], acc3[i][j]);
    }
    __syncthreads();
  }
#pragma unroll
  for (int i = 0; i < 8; ++i) {
    float mx = -__builtin_inff();
#pragma unroll
    for (int j = 0; j < 8; ++j) {
      float v = fmaf(acc3[i][j], a3r[i], d3r[i]);
      mx = fmaxf(mx, v);
    }
    float o = __shfl_xor(mx, 32, 64);
    mx = fmaxf(mx, o);
    if ((tcol & 1) == 0) {
      int g = tcol >> 1;
      int bs = ch * 4 + g;
      int b = bs / S_;
      int s = bs - b * S_;
      out1[((size_t)(b * 256 + tm3 * 8 + i)) * S_ + s] = fmaxf(mx, 0.f);
    }
  }
}

__global__ void diag_kernel(float* out, float v) {
  if (threadIdx.x == 0 && blockIdx.x == 0) out[0] = v;
}

extern "C" void kernel_launch(void* const* d_in, const int* in_sizes, int n_in,
                              void* d_out, int out_size, void* d_ws, size_t ws_size,
                              hipStream_t stream) {
  const float* xy  = (const float*)d_in[0];
  const float* fea = (const float*)d_in[1];
  const float* W1  = (const float*)d_in[2];
  const float* b1  = (const float*)d_in[3];
  const float* g1  = (const float*)d_in[4];
  const float* be1 = (const float*)d_in[5];
  const float* W2  = (const float*)d_in[6];
  const float* b2  = (const float*)d_in[7];
  const float* g2  = (const float*)d_in[8];
  const float* be2 = (const float*)d_in[9];
  const float* W3  = (const float*)d_in[10];
  const float* b3  = (const float*)d_in[11];
  const float* g3  = (const float*)d_in[12];
  const float* be3 = (const float*)d_in[13];
  (void)b2; (void)b3;
  float* out = (float*)d_out;
  float* out1 = out + B_ * 2 * S_;

  char* w = (char*)d_ws;
  size_t off = 0;
  auto take = [&](size_t bytes) -> void* {
    void* p = w + off;
    off += (bytes + 255) & ~(size_t)255;
    return p;
  };
  int*    fps_idx = (int*)take((size_t)B_ * S_ * 4);
  float*  new_xyz = (float*)take((size_t)B_ * S_ * 2 * 4);
  int*    knn_sel = (int*)take((size_t)NF_ * 4);
  float*  P       = (float*)take((size_t)B_ * N_ * 64 * 4);   // 8.4 MB
  float*  Y1      = (float*)take((size_t)64 * NF_ * 4);       // 67.2 MB
  double* Sy1     = (double*)take(64 * 8);
  double* Sq1     = (double*)take(64 * 8);
  float*  A1      = (float*)take(64 * 4);
  float*  Bc1     = (float*)take(64 * 4);
  float*  partsA  = (float*)take((size_t)512 * 256 * 4);
  double* Sy2     = (double*)take(128 * 8);
  double* Sq2     = (double*)take(128 * 8);
  float*  A2      = (float*)take(128 * 4);
  float*  D2      = (float*)take(128 * 4);
  float*  partsB  = (float*)take((size_t)256 * 512 * 4);
  double* Sy3     = (double*)take(256 * 8);
  double* Sq3     = (double*)take(256 * 8);
  float*  A3      = (float*)take(256 * 4);
  float*  D3      = (float*)take(256 * 4);

  if (off > ws_size) {
    diag_kernel<<<1, 64, 0, stream>>>(out, (float)(ws_size >> 20));
    return;
  }

  fps_kernel<<<B_, 64, 0, stream>>>(xy, fps_idx, new_xyz, out);
  knn_kernel<<<dim3((S_ + 15) / 16, B_), 256, 0, stream>>>(xy, fps_idx, knn_sel);
  pk_kernel<<<B_ * 32, 256, 0, stream>>>(fea, W1, P);
  yk1_kernel<<<NF_ / 256, 256, 0, stream>>>(xy, knn_sel, new_xyz, P, W1, b1, Y1);

  rowstats_kernel<<<64, 1024, 0, stream>>>(Y1, Sy1, Sq1);
  absch_kernel<<<1, 64, 0, stream>>>(Sy1, Sq1, g1, be1, A1, Bc1, 64);

  passA_kernel<<<512, 256, 0, stream>>>(Y1, W2, A1, Bc1, partsA);
  redab_kernel<<<1, 128, 0, stream>>>(partsA, Sy2, Sq2, 512, 128);
  absch_kernel<<<1, 128, 0, stream>>>(Sy2, Sq2, g2, be2, A2, D2, 128);

  passB_kernel<<<256, 256, 0, stream>>>(Y1, W2, W3, A1, Bc1, A2, D2, partsB);
  redab_kernel<<<1, 256, 0, stream>>>(partsB, Sy3, Sq3, 256, 256);
  absch_kernel<<<1, 256, 0, stream>>>(Sy3, Sq3, g3, be3, A3, D3, 256);

  final_kernel<<<NCH_, 256, 0, stream>>>(Y1, W2, W3, A1, Bc1, A2, D2, A3, D3, out1);
}